// Round 1
// baseline (667.135 us; speedup 1.0000x reference)
//
#include <hip/hip_runtime.h>

// Problem constants (fixed by the reference setup)
#define NN 100000          // N_NODES
#define NE 1600000         // N_EDGES
#define IND 128            // IN_DIM
#define FD 32              // OUT_DIM
#define NH 8               // HEADS
#define HF 256             // NH*FD
#define ETOT 1700000       // NE + NN self loops

// ---------------------------------------------------------------------------
// K1: projection GEMM  h[n][c] = sum_k X[n][k] * W[k][c]
// 16 nodes x 256 cols per block, 256 threads, LDS-staged X tile.
// thread t: cg = t>>2 -> 4 contiguous cols, ng = t&3 -> 4 nodes (x4 groups)
// ---------------------------------------------------------------------------
__global__ __launch_bounds__(256) void k_gemm(const float* __restrict__ X,
                                              const float* __restrict__ W,
                                              float* __restrict__ Hout) {
  // pad rows to 132 floats to break the 128-float power-of-2 LDS stride
  __shared__ __align__(16) float Xs[16 * 132];
  const int n0 = blockIdx.x * 16;
  const int t = threadIdx.x;
#pragma unroll
  for (int j = 0; j < 8; ++j) {
    int idx = t + j * 256;          // 0..2047
    int r = idx >> 7, c = idx & 127;
    Xs[r * 132 + c] = X[(n0 + r) * IND + c];
  }
  __syncthreads();

  const int cg = t >> 2;            // 0..63
  const int c0 = cg * 4;            // col group (16B aligned)
  const int ng = t & 3;             // node group

  float4 acc[4];
#pragma unroll
  for (int i = 0; i < 4; ++i) acc[i] = make_float4(0.f, 0.f, 0.f, 0.f);

  for (int k0 = 0; k0 < IND; k0 += 4) {
    const float4 w0 = *(const float4*)(W + (k0 + 0) * HF + c0);
    const float4 w1 = *(const float4*)(W + (k0 + 1) * HF + c0);
    const float4 w2 = *(const float4*)(W + (k0 + 2) * HF + c0);
    const float4 w3 = *(const float4*)(W + (k0 + 3) * HF + c0);
#pragma unroll
    for (int i = 0; i < 4; ++i) {
      const float4 xv = *(const float4*)(Xs + (ng * 4 + i) * 132 + k0);
      acc[i].x += xv.x * w0.x + xv.y * w1.x + xv.z * w2.x + xv.w * w3.x;
      acc[i].y += xv.x * w0.y + xv.y * w1.y + xv.z * w2.y + xv.w * w3.y;
      acc[i].z += xv.x * w0.z + xv.y * w1.z + xv.z * w2.z + xv.w * w3.z;
      acc[i].w += xv.x * w0.w + xv.y * w1.w + xv.z * w2.w + xv.w * w3.w;
    }
  }
#pragma unroll
  for (int i = 0; i < 4; ++i) {
    *(float4*)(Hout + (n0 + ng * 4 + i) * HF + c0) = acc[i];
  }
}

// ---------------------------------------------------------------------------
// K2: per-(node,head) attention logits
// ---------------------------------------------------------------------------
__global__ __launch_bounds__(256) void k_logits(const float* __restrict__ Hh,
                                                const float* __restrict__ att_src,
                                                const float* __restrict__ att_dst,
                                                float* __restrict__ a_s,
                                                float* __restrict__ a_d) {
  int tid = blockIdx.x * 256 + threadIdx.x;
  if (tid >= NN * NH) return;
  int n = tid >> 3, hh = tid & 7;
  const float4* hv = (const float4*)(Hh + n * HF + hh * FD);
  const float4* v1 = (const float4*)(att_src + hh * FD);
  const float4* v2 = (const float4*)(att_dst + hh * FD);
  float s1 = 0.f, s2 = 0.f;
#pragma unroll
  for (int j = 0; j < 8; ++j) {
    float4 h4 = hv[j], a1 = v1[j], a2 = v2[j];
    s1 += h4.x * a1.x + h4.y * a1.y + h4.z * a1.z + h4.w * a1.w;
    s2 += h4.x * a2.x + h4.y * a2.y + h4.z * a2.z + h4.w * a2.w;
  }
  a_s[tid] = s1;
  a_d[tid] = s2;
}

// ---------------------------------------------------------------------------
// K3: softmax denominators (no max pass: logits are bounded ~[-8,8], exp is
// safe in fp32 and alpha/denom is mathematically identical to the reference)
// one thread per (edge, head); self loops are edges [NE, NE+NN)
// ---------------------------------------------------------------------------
__global__ __launch_bounds__(256) void k_denom(const int* __restrict__ ei,
                                               const float* __restrict__ a_s,
                                               const float* __restrict__ a_d,
                                               float* __restrict__ den) {
  int tid = blockIdx.x * 256 + threadIdx.x;
  if (tid >= ETOT * NH) return;
  int e = tid >> 3, hh = tid & 7;
  int s, d;
  if (e < NE) { s = ei[e]; d = ei[NE + e]; } else { s = d = e - NE; }
  float lg = a_s[s * NH + hh] + a_d[d * NH + hh];
  lg = lg > 0.f ? lg : 0.2f * lg;
  __hip_atomic_fetch_add(&den[d * NH + hh], __expf(lg),
                         __ATOMIC_RELAXED, __HIP_MEMORY_SCOPE_AGENT);
}

// ---------------------------------------------------------------------------
// K4: aggregation. One thread per (edge, f). Head sum collapsed in registers
// before the atomic -> 32 atomics/edge instead of 256.
// ---------------------------------------------------------------------------
__global__ __launch_bounds__(256) void k_aggr(const int* __restrict__ ei,
                                              const float* __restrict__ a_s,
                                              const float* __restrict__ a_d,
                                              const float* __restrict__ den,
                                              const float* __restrict__ Hh,
                                              float* __restrict__ oac) {
  int tid = blockIdx.x * 256 + threadIdx.x;
  if (tid >= ETOT * FD) return;
  int e = tid >> 5, f = tid & 31;
  int s, d;
  if (e < NE) { s = ei[e]; d = ei[NE + e]; } else { s = d = e - NE; }
  const float* hs = Hh + s * HF + f;
  float msg = 0.f;
#pragma unroll
  for (int hh = 0; hh < NH; ++hh) {
    float lg = a_s[s * NH + hh] + a_d[d * NH + hh];
    lg = lg > 0.f ? lg : 0.2f * lg;
    float al = __expf(lg) / (den[d * NH + hh] + 1e-16f);
    msg += al * hs[hh * FD];
  }
  __hip_atomic_fetch_add(&oac[d * FD + f], msg,
                         __ATOMIC_RELAXED, __HIP_MEMORY_SCOPE_AGENT);
}

// ---------------------------------------------------------------------------
// K5: mean over heads + bias
// ---------------------------------------------------------------------------
__global__ __launch_bounds__(256) void k_final(const float* __restrict__ oac,
                                               const float* __restrict__ bias,
                                               float* __restrict__ out) {
  int tid = blockIdx.x * 256 + threadIdx.x;
  if (tid >= NN * FD) return;
  out[tid] = oac[tid] * 0.125f + bias[tid & 31];
}

// ---------------------------------------------------------------------------
// Workspace layout (floats):
//   Hh   [0,          25,600,000)   102.4 MB
//   a_s  [25,600,000, 26,400,000)     3.2 MB
//   a_d  [26,400,000, 27,200,000)     3.2 MB
//   den  [27,200,000, 28,000,000)     3.2 MB
//   oac  [28,000,000, 31,200,000)    12.8 MB
// total 124.8 MB
// ---------------------------------------------------------------------------
extern "C" void kernel_launch(void* const* d_in, const int* in_sizes, int n_in,
                              void* d_out, int out_size, void* d_ws, size_t ws_size,
                              hipStream_t stream) {
  const float* X       = (const float*)d_in[0];
  const int*   ei      = (const int*)d_in[1];
  const float* W       = (const float*)d_in[2];
  const float* att_src = (const float*)d_in[3];
  const float* att_dst = (const float*)d_in[4];
  const float* bias    = (const float*)d_in[5];
  float* out = (float*)d_out;
  float* ws  = (float*)d_ws;

  float* Hh  = ws;
  float* a_s = ws + 25600000;
  float* a_d = ws + 26400000;
  float* den = ws + 27200000;
  float* oac = ws + 28000000;

  // zero den + oac (contiguous 4M floats); ws is poisoned 0xAA before launch
  hipMemsetAsync(den, 0, (size_t)4000000 * sizeof(float), stream);

  k_gemm  <<<NN / 16, 256, 0, stream>>>(X, W, Hh);
  k_logits<<<(NN * NH + 255) / 256, 256, 0, stream>>>(Hh, att_src, att_dst, a_s, a_d);
  k_denom <<<(ETOT * NH + 255) / 256, 256, 0, stream>>>(ei, a_s, a_d, den);
  k_aggr  <<<(ETOT * FD + 255) / 256, 256, 0, stream>>>(ei, a_s, a_d, den, Hh, oac);
  k_final <<<(NN * FD + 255) / 256, 256, 0, stream>>>(oac, bias, out);
}